// Round 1
// baseline (480.725 us; speedup 1.0000x reference)
//
#include <hip/hip_runtime.h>
#include <hip/hip_bf16.h>

typedef __bf16 bf16x8 __attribute__((ext_vector_type(8)));
typedef float f32x4 __attribute__((ext_vector_type(4)));

__device__ __forceinline__ void gload_lds16(const void* g, void* l) {
  __builtin_amdgcn_global_load_lds(
      (const __attribute__((address_space(1))) void*)g,
      (__attribute__((address_space(3))) void*)l, 16, 0, 0);
}

// ---------------- f32 -> bf16 convert ----------------
__global__ __launch_bounds__(256) void k_f2b(const float* __restrict__ s,
                                             __bf16* __restrict__ d, int n) {
  int i = (blockIdx.x * 256 + threadIdx.x) * 4;
  if (i < n) {
    const float4 v = *(const float4*)(s + i);
    d[i + 0] = (__bf16)v.x;
    d[i + 1] = (__bf16)v.y;
    d[i + 2] = (__bf16)v.z;
    d[i + 3] = (__bf16)v.w;
  }
}

// ---------------- NT GEMM: C[M,N] = A[M,K] * B[N,K]^T ----------------
// 128x128 tile, BK=64, 4 waves (2x2), each wave 64x64 (4x4 of 16x16 MFMA).
// EPI 0: scatter k/q/vT bf16 for attention. EPI 1: +bias, exact GELU -> bf16.
// EPI 2: +bias +resid -> f32 out.
template <int EPI>
__global__ __launch_bounds__(256) void k_gemm(
    const __bf16* __restrict__ A, const __bf16* __restrict__ B, int N, int K,
    const float* __restrict__ bias, const float* __restrict__ resid,
    float* __restrict__ outf, __bf16* __restrict__ outb,
    __bf16* __restrict__ ok, __bf16* __restrict__ oq, __bf16* __restrict__ ovt) {
  __shared__ __align__(16) __bf16 As[128 * 64];
  __shared__ __align__(16) __bf16 Bs[128 * 64];
  const int tid = threadIdx.x;
  const int lane = tid & 63, wid = tid >> 6;
  const int wr = wid >> 1, wc = wid & 1;
  const int lr = lane & 15, lh = lane >> 4;
  const int m0 = blockIdx.y * 128, n0 = blockIdx.x * 128;
  f32x4 acc[4][4] = {};
  for (int k0 = 0; k0 < K; k0 += 64) {
    __syncthreads();
#pragma unroll
    for (int j = 0; j < 4; ++j) {
      int chunk = (wid * 4 + j) * 64 + lane;  // 16B chunk id, 0..1023
      int row = chunk >> 3, c8 = chunk & 7;
      gload_lds16(A + (size_t)(m0 + row) * K + (k0 + c8 * 8), &As[chunk * 8]);
      gload_lds16(B + (size_t)(n0 + row) * K + (k0 + c8 * 8), &Bs[chunk * 8]);
    }
    __syncthreads();
#pragma unroll
    for (int ks = 0; ks < 2; ++ks) {
      bf16x8 af[4], bfr[4];
#pragma unroll
      for (int mi = 0; mi < 4; ++mi)
        af[mi] = *(const bf16x8*)&As[(wr * 64 + mi * 16 + lr) * 64 + ks * 32 + lh * 8];
#pragma unroll
      for (int ni = 0; ni < 4; ++ni)
        bfr[ni] = *(const bf16x8*)&Bs[(wc * 64 + ni * 16 + lr) * 64 + ks * 32 + lh * 8];
#pragma unroll
      for (int mi = 0; mi < 4; ++mi)
#pragma unroll
        for (int ni = 0; ni < 4; ++ni)
          acc[mi][ni] = __builtin_amdgcn_mfma_f32_16x16x32_bf16(
              af[mi], bfr[ni], acc[mi][ni], 0, 0, 0);
    }
  }
#pragma unroll
  for (int mi = 0; mi < 4; ++mi) {
#pragma unroll
    for (int j = 0; j < 4; ++j) {
      const int row = m0 + wr * 64 + mi * 16 + lh * 4 + j;
#pragma unroll
      for (int ni = 0; ni < 4; ++ni) {
        const int col = n0 + wc * 64 + ni * 16 + lr;
        float v = acc[mi][ni][j];
        if constexpr (EPI == 0) {
          const int which = col >> 10, c = col & 1023;
          const int ih = c >> 6, hh = c & 63;
          const int bb = row >> 11, pp = row & 2047;
          const int bi = bb * 16 + ih;
          if (which == 0)
            ok[((size_t)bi * 2048 + pp) * 64 + hh] = (__bf16)v;
          else if (which == 1)
            oq[((size_t)bi * 2048 + pp) * 64 + hh] = (__bf16)v;
          else
            ovt[((size_t)bi * 64 + hh) * 2048 + pp] = (__bf16)v;
        } else if constexpr (EPI == 1) {
          float h = v + bias[col];
          float g = 0.5f * h * (1.f + erff(h * 0.70710678118f));
          outb[(size_t)row * N + col] = (__bf16)g;
        } else {
          outf[(size_t)row * N + col] = v + bias[col] + resid[(size_t)row * N + col];
        }
      }
    }
  }
}

// ---------------- flash attention (causal, UNSCALED softmax) ----------------
// 1 wave per (b, i, 16-row q tile). k-tiles of 32. Online softmax in f32.
__global__ __launch_bounds__(64) void k_attn(const __bf16* __restrict__ kb,
                                             const __bf16* __restrict__ qb,
                                             const __bf16* __restrict__ vt,
                                             float* __restrict__ z) {
  const int lane = threadIdx.x;
  const int lr = lane & 15, lh = lane >> 4;
  const int qt = blockIdx.x, ih = blockIdx.y, b = blockIdx.z;
  const int bi = b * 16 + ih;
  const int q0 = qt * 16;
  const __bf16* kbase = kb + (size_t)bi * 2048 * 64;
  const __bf16* qbase = qb + (size_t)bi * 2048 * 64;
  const __bf16* vbase = vt + (size_t)bi * 64 * 2048;

  bf16x8 aq[2];
#pragma unroll
  for (int ks = 0; ks < 2; ++ks)
    aq[ks] = *(const bf16x8*)(qbase + (size_t)(q0 + lr) * 64 + ks * 32 + lh * 8);

  f32x4 o[4] = {};
  float mrow[4], lrow[4];
#pragma unroll
  for (int j = 0; j < 4; ++j) { mrow[j] = -INFINITY; lrow[j] = 0.f; }

  __shared__ __align__(16) __bf16 plds[16 * 40];  // padded stride 40

  const int nk = (q0 + 16 + 31) / 32;
  for (int kt = 0; kt < nk; ++kt) {
    const int k0 = kt * 32;
    f32x4 s[2] = {};
#pragma unroll
    for (int ks = 0; ks < 2; ++ks) {
      bf16x8 bk0 = *(const bf16x8*)(kbase + (size_t)(k0 + lr) * 64 + ks * 32 + lh * 8);
      bf16x8 bk1 = *(const bf16x8*)(kbase + (size_t)(k0 + 16 + lr) * 64 + ks * 32 + lh * 8);
      s[0] = __builtin_amdgcn_mfma_f32_16x16x32_bf16(aq[ks], bk0, s[0], 0, 0, 0);
      s[1] = __builtin_amdgcn_mfma_f32_16x16x32_bf16(aq[ks], bk1, s[1], 0, 0, 0);
    }
    if (kt == nk - 1) {  // only last tile can straddle the diagonal
#pragma unroll
      for (int n = 0; n < 2; ++n)
#pragma unroll
        for (int j = 0; j < 4; ++j) {
          int qpos = q0 + lh * 4 + j;
          int kpos = k0 + n * 16 + lr;
          if (kpos > qpos) s[n][j] = -1e10f;
        }
    }
    float tmax[4], tsum[4], scale[4], p[2][4];
#pragma unroll
    for (int j = 0; j < 4; ++j) tmax[j] = fmaxf(s[0][j], s[1][j]);
#pragma unroll
    for (int m = 1; m < 16; m <<= 1)
#pragma unroll
      for (int j = 0; j < 4; ++j) tmax[j] = fmaxf(tmax[j], __shfl_xor(tmax[j], m));
#pragma unroll
    for (int j = 0; j < 4; ++j) {
      float mn = fmaxf(mrow[j], tmax[j]);
      scale[j] = __expf(mrow[j] - mn);
      mrow[j] = mn;
    }
#pragma unroll
    for (int n = 0; n < 2; ++n)
#pragma unroll
      for (int j = 0; j < 4; ++j) p[n][j] = __expf(s[n][j] - mrow[j]);
#pragma unroll
    for (int j = 0; j < 4; ++j) tsum[j] = p[0][j] + p[1][j];
#pragma unroll
    for (int m = 1; m < 16; m <<= 1)
#pragma unroll
      for (int j = 0; j < 4; ++j) tsum[j] += __shfl_xor(tsum[j], m);
#pragma unroll
    for (int j = 0; j < 4; ++j) lrow[j] = lrow[j] * scale[j] + tsum[j];
#pragma unroll
    for (int ht = 0; ht < 4; ++ht)
#pragma unroll
      for (int j = 0; j < 4; ++j) o[ht][j] *= scale[j];

    __syncthreads();
#pragma unroll
    for (int n = 0; n < 2; ++n)
#pragma unroll
      for (int j = 0; j < 4; ++j)
        plds[(lh * 4 + j) * 40 + n * 16 + lr] = (__bf16)p[n][j];
    __syncthreads();
    bf16x8 pa = *(const bf16x8*)&plds[lr * 40 + lh * 8];
#pragma unroll
    for (int ht = 0; ht < 4; ++ht) {
      bf16x8 bv = *(const bf16x8*)(vbase + (size_t)(ht * 16 + lr) * 2048 + k0 + lh * 8);
      o[ht] = __builtin_amdgcn_mfma_f32_16x16x32_bf16(pa, bv, o[ht], 0, 0, 0);
    }
  }
  float* zr = z + (size_t)b * 2048 * 1024;
#pragma unroll
  for (int j = 0; j < 4; ++j) {
    float inv = 1.f / lrow[j];
    int q = q0 + lh * 4 + j;
#pragma unroll
    for (int ht = 0; ht < 4; ++ht)
      zr[(size_t)q * 1024 + ih * 64 + ht * 16 + lr] = o[ht][j] * inv;
  }
}

// ---------------- residual + custom LayerNorm ----------------
__global__ __launch_bounds__(256) void k_ln(const float* __restrict__ x,
                                            const float* __restrict__ z,
                                            const float* __restrict__ wln,
                                            const float* __restrict__ bln,
                                            float* __restrict__ y,
                                            __bf16* __restrict__ yb) {
  const int row = blockIdx.x;
  const int t = threadIdx.x;
  const int lane = t & 63, wid = t >> 6;
  const float4 xv = ((const float4*)(x + (size_t)row * 1024))[t];
  const float4 zv = ((const float4*)(z + (size_t)row * 1024))[t];
  float v0 = xv.x + zv.x, v1 = xv.y + zv.y, v2 = xv.z + zv.z, v3 = xv.w + zv.w;
  __shared__ float red[4];
  float s = v0 + v1 + v2 + v3;
#pragma unroll
  for (int m = 1; m < 64; m <<= 1) s += __shfl_xor(s, m);
  if (lane == 0) red[wid] = s;
  __syncthreads();
  const float mean = (red[0] + red[1] + red[2] + red[3]) * (1.f / 1024.f);
  const float c0 = v0 - mean, c1 = v1 - mean, c2 = v2 - mean, c3 = v3 - mean;
  float ss = c0 * c0 + c1 * c1 + c2 * c2 + c3 * c3;
#pragma unroll
  for (int m = 1; m < 64; m <<= 1) ss += __shfl_xor(ss, m);
  __syncthreads();
  if (lane == 0) red[wid] = ss;
  __syncthreads();
  const float var = (red[0] + red[1] + red[2] + red[3]) * (1.f / 1023.f);
  const float inv = 1.f / (sqrtf(var) + 1e-4f);
  const float4 wv = ((const float4*)wln)[t];
  const float4 bv = ((const float4*)bln)[t];
  float y0 = c0 * inv * wv.x + bv.x;
  float y1 = c1 * inv * wv.y + bv.y;
  float y2 = c2 * inv * wv.z + bv.z;
  float y3 = c3 * inv * wv.w + bv.w;
  float4 yo; yo.x = y0; yo.y = y1; yo.z = y2; yo.w = y3;
  ((float4*)(y + (size_t)row * 1024))[t] = yo;
  __bf16* yd = yb + (size_t)row * 1024 + t * 4;
  yd[0] = (__bf16)y0; yd[1] = (__bf16)y1; yd[2] = (__bf16)y2; yd[3] = (__bf16)y3;
}

// ---------------- launch ----------------
extern "C" void kernel_launch(void* const* d_in, const int* in_sizes, int n_in,
                              void* d_out, int out_size, void* d_ws, size_t ws_size,
                              hipStream_t stream) {
  const float* x = (const float*)d_in[0];
  const float* W_K = (const float*)d_in[1];
  const float* W_Q = (const float*)d_in[2];
  const float* W_V = (const float*)d_in[3];
  const float* w_ln = (const float*)d_in[4];
  const float* b_ln = (const float*)d_in[5];
  const float* W_in = (const float*)d_in[6];
  const float* b_in = (const float*)d_in[7];
  const float* W_out = (const float*)d_in[8];
  const float* b_out = (const float*)d_in[9];
  float* out = (float*)d_out;

  char* ws = (char*)d_ws;
  const size_t NEEDED = 132120576;  // ~126 MB
  if (ws_size < NEEDED) return;

  __bf16* xb   = (__bf16*)(ws);                //  8 MB  [4096,1024]
  __bf16* wqkv = (__bf16*)(ws + 8388608);      //  6 MB  [3072,1024] K,Q,V stacked
  __bf16* winb = (__bf16*)(ws + 14680064);     //  8 MB  [4096,1024]
  __bf16* woutb= (__bf16*)(ws + 23068672);     //  8 MB  [1024,4096]
  __bf16* kbuf = (__bf16*)(ws + 31457280);     //  8 MB  [b,i,p,h]
  __bf16* qbuf = (__bf16*)(ws + 39845888);     //  8 MB  [b,i,p,h]
  __bf16* vtb  = (__bf16*)(ws + 48234496);     //  8 MB  [b,i,h,p]
  float*  zb   = (float*)(ws + 56623104);      // 16 MB  [b,p,1024]
  float*  yf   = (float*)(ws + 73400320);      // 16 MB  LN out f32
  __bf16* ybb  = (__bf16*)(ws + 90177536);     //  8 MB  LN out bf16
  __bf16* hact = (__bf16*)(ws + 98566144);     // 32 MB  [4096,4096]

  k_f2b<<<4096, 256, 0, stream>>>(x, xb, 4194304);
  k_f2b<<<1024, 256, 0, stream>>>(W_K, wqkv, 1048576);
  k_f2b<<<1024, 256, 0, stream>>>(W_Q, wqkv + 1048576, 1048576);
  k_f2b<<<1024, 256, 0, stream>>>(W_V, wqkv + 2097152, 1048576);
  k_f2b<<<4096, 256, 0, stream>>>(W_in, winb, 4194304);
  k_f2b<<<4096, 256, 0, stream>>>(W_out, woutb, 4194304);

  // QKV projection: [4096,1024] x [3072,1024]^T
  k_gemm<0><<<dim3(24, 32), 256, 0, stream>>>(xb, wqkv, 3072, 1024, nullptr,
                                              nullptr, nullptr, nullptr, kbuf,
                                              qbuf, vtb);
  // attention
  k_attn<<<dim3(128, 16, 2), 64, 0, stream>>>(kbuf, qbuf, vtb, zb);
  // residual + LN
  k_ln<<<4096, 256, 0, stream>>>(x, zb, w_ln, b_ln, yf, ybb);
  // MLP in + GELU: [4096,1024] x [4096,1024]^T
  k_gemm<1><<<dim3(32, 32), 256, 0, stream>>>(ybb, winb, 4096, 1024, b_in,
                                              nullptr, nullptr, hact, nullptr,
                                              nullptr, nullptr);
  // MLP out + bias + residual: [4096,4096] x [1024,4096]^T
  k_gemm<2><<<dim3(8, 32), 256, 0, stream>>>(hact, woutb, 1024, 4096, b_out,
                                             yf, out, nullptr, nullptr,
                                             nullptr, nullptr);
}